// Round 3
// baseline (610.685 us; speedup 1.0000x reference)
//
#include <hip/hip_runtime.h>
#include <hip/hip_bf16.h>

typedef unsigned short u16;
typedef __bf16 bf16x8 __attribute__((ext_vector_type(8)));
typedef float f32x4 __attribute__((ext_vector_type(4)));

__device__ __forceinline__ u16 f2bf(float f) {
    union { float f; unsigned int u; } v; v.f = f;
    unsigned int u = v.u;
    unsigned int r = (u + 0x7fffu + ((u >> 16) & 1u)) >> 16;
    return (u16)r;
}
__device__ __forceinline__ float bf2f(u16 b) {
    union { unsigned int u; float f; } v; v.u = ((unsigned int)b) << 16;
    return v.f;
}

__device__ __forceinline__ void glds16(const u16* g, u16* l) {
    __builtin_amdgcn_global_load_lds(
        (__attribute__((address_space(1))) void*)(g),
        (__attribute__((address_space(3))) void*)(l), 16, 0, 0);
}

// ---------------- cast fp32 -> bf16 (vectorized) ----------------
__global__ __launch_bounds__(256) void cast_bf16_kernel(const float* __restrict__ src,
                                                        u16* __restrict__ dst, int n4) {
    int i = blockIdx.x * 256 + threadIdx.x;
    if (i >= n4) return;
    float4 v = ((const float4*)src)[i];
    ushort4 o;
    o.x = f2bf(v.x); o.y = f2bf(v.y); o.z = f2bf(v.z); o.w = f2bf(v.w);
    ((ushort4*)dst)[i] = o;
}

// ---------------- transpose+cast weights: WT[n][k] = W[k][n] ----------------
__global__ __launch_bounds__(256) void transpose_cast_kernel(
    const float* __restrict__ Wq, const float* __restrict__ Wk, const float* __restrict__ Wv,
    const float* __restrict__ Wg, const float* __restrict__ Wo,
    u16* __restrict__ WqT, u16* __restrict__ WkvT, u16* __restrict__ WgT, u16* __restrict__ WoT) {
    __shared__ float tile[32][33];
    const float* src; u16* dst;
    switch (blockIdx.z) {
        case 0: src = Wq; dst = WqT; break;
        case 1: src = Wk; dst = WkvT; break;
        case 2: src = Wv; dst = WkvT + (size_t)1024 * 1024; break;
        case 3: src = Wg; dst = WgT; break;
        default: src = Wo; dst = WoT; break;
    }
    int n0 = blockIdx.x * 32, k0 = blockIdx.y * 32;
    int tx = threadIdx.x, ty = threadIdx.y;   // (32, 8)
    #pragma unroll
    for (int j = 0; j < 4; j++)
        tile[ty + j * 8][tx] = src[(size_t)(k0 + ty + j * 8) * 1024 + n0 + tx];
    __syncthreads();
    #pragma unroll
    for (int j = 0; j < 4; j++)
        dst[(size_t)(n0 + ty + j * 8) * 1024 + k0 + tx] = f2bf(tile[tx][ty + j * 8]);
}

// ---------------- 128^2 bf16 MFMA GEMM (m97 structure) for the small GEMMs ----------------
template <int EPI>
__global__ __launch_bounds__(256) void gemm_bf16(
    const u16* __restrict__ A, const u16* __restrict__ B, int ldc,
    u16* __restrict__ Cbf, const float* __restrict__ bias,
    const u16* __restrict__ mul_src, const float* __restrict__ add_src,
    float* __restrict__ Cf) {
    constexpr int K = 1024;
    const int tid = threadIdx.x;
    const int w = tid >> 6, l = tid & 63;
    const int lr = l & 15, lg = l >> 4;
    const int wr = w >> 1, wc = w & 1;
    const int m0 = blockIdx.y * 128, n0 = blockIdx.x * 128;

    __shared__ u16 As[128 * 64];
    __shared__ u16 Bs[128 * 64];

    const f32x4 fz = {0.f, 0.f, 0.f, 0.f};
    f32x4 acc[4][4];
    #pragma unroll
    for (int i = 0; i < 4; i++)
        #pragma unroll
        for (int j = 0; j < 4; j++) acc[i][j] = fz;

    const int lane_row = l >> 3;
    const int lane_sl  = l & 7;
    const int src_ch   = lane_sl ^ lane_row;
    const u16* Ab = A + (size_t)(m0 + w * 32 + lane_row) * K + src_ch * 8;
    const u16* Bb = B + (size_t)(n0 + w * 32 + lane_row) * K + src_ch * 8;

    for (int kt = 0; kt < K; kt += 64) {
        __syncthreads();
        #pragma unroll
        for (int j = 0; j < 4; j++) {
            glds16(Ab + (size_t)j * 8 * K + kt, As + (w * 32 + j * 8) * 64);
            glds16(Bb + (size_t)j * 8 * K + kt, Bs + (w * 32 + j * 8) * 64);
        }
        __syncthreads();
        #pragma unroll
        for (int kk = 0; kk < 2; kk++) {
            bf16x8 af[4], bfr[4];
            #pragma unroll
            for (int mi = 0; mi < 4; mi++) {
                int row = wr * 64 + mi * 16 + lr;
                int ch = (kk * 4 + lg) ^ (row & 7);
                af[mi] = *(const bf16x8*)(As + row * 64 + ch * 8);
            }
            #pragma unroll
            for (int ni = 0; ni < 4; ni++) {
                int row = wc * 64 + ni * 16 + lr;
                int ch = (kk * 4 + lg) ^ (row & 7);
                bfr[ni] = *(const bf16x8*)(Bs + row * 64 + ch * 8);
            }
            #pragma unroll
            for (int mi = 0; mi < 4; mi++)
                #pragma unroll
                for (int ni = 0; ni < 4; ni++)
                    acc[mi][ni] = __builtin_amdgcn_mfma_f32_16x16x32_bf16(
                        af[mi], bfr[ni], acc[mi][ni], 0, 0, 0);
        }
    }

    #pragma unroll
    for (int mi = 0; mi < 4; mi++) {
        #pragma unroll
        for (int ni = 0; ni < 4; ni++) {
            #pragma unroll
            for (int r = 0; r < 4; r++) {
                int gm = m0 + wr * 64 + mi * 16 + lg * 4 + r;
                int gn = n0 + wc * 64 + ni * 16 + lr;
                float v = acc[mi][ni][r];
                if (EPI == 0) {
                    Cbf[(size_t)gm * ldc + gn] = f2bf(v);
                } else if (EPI == 2) {
                    float g = v + bias[gn];
                    float a = bf2f(mul_src[(size_t)gm * ldc + gn]);
                    float sg = 1.f / (1.f + __expf(-g));
                    Cbf[(size_t)gm * ldc + gn] = f2bf(a * sg);
                } else {
                    Cf[(size_t)gm * ldc + gn] = v + bias[gn] + add_src[(size_t)gm * ldc + gn];
                }
            }
        }
    }
}

// ---------------- 256^2 8-wave phase-split GEMM (T2+T3+T4+T5) ----------------
// C[M,N] = A[M,1024] @ B[N,1024]^T, bf16 out. 512 threads = 8 waves (2Mx4N),
// per-wave 128x64 output. BK=64, double-buffered 128KiB LDS, 4 phases/K-tile,
// counted vmcnt(4) once per K-tile.
__global__ __launch_bounds__(512, 2) void gemm256_bf16(
    const u16* __restrict__ A, const u16* __restrict__ B, int ldc,
    u16* __restrict__ Cbf) {
    constexpr int K = 1024;
    constexpr int NT = 16;      // K tiles
    const int tid = threadIdx.x;
    const int w = tid >> 6, l = tid & 63;
    const int lr = l & 15, lg = l >> 4;
    const int wr = w >> 2, wc = w & 3;
    const int m0 = blockIdx.y * 256, n0 = blockIdx.x * 256;

    __shared__ u16 As[2][256 * 64];
    __shared__ u16 Bs[2][256 * 64];

    const int lrow8 = l >> 3;                    // 0..7
    const int src_ch = (l & 7) ^ (lrow8 & 7);    // T2 pre-swizzled source chunk

    // stage A quarter q (64 rows at q*64) of K-tile at column kt into buffer buf
    auto stageA = [&](int buf, int q, int kt) {
        const u16* src = A + (size_t)(m0 + q * 64 + w * 8 + lrow8) * K + kt + src_ch * 8;
        glds16(src, &As[buf][(q * 64 + w * 8) * 64]);
    };
    // stage B nh-rows (32-row stripes), half selects rows [half*128, half*128+128)
    auto stageB = [&](int buf, int nh, int half, int kt) {
        int row = half * 128 + (w >> 2) * 64 + nh * 32 + (w & 3) * 8;
        const u16* src = B + (size_t)(n0 + row + lrow8) * K + kt + src_ch * 8;
        glds16(src, &Bs[buf][row * 64]);
    };

    const f32x4 fz = {0.f, 0.f, 0.f, 0.f};
    f32x4 acc[8][4];
    #pragma unroll
    for (int i = 0; i < 8; i++)
        #pragma unroll
        for (int j = 0; j < 4; j++) acc[i][j] = fz;

    // prologue: tile0 fully into buf0; tile1 A02+B0 into buf1
    stageA(0, 0, 0); stageA(0, 2, 0);
    stageB(0, 0, 0, 0); stageB(0, 0, 1, 0);
    stageA(0, 1, 0); stageA(0, 3, 0);
    stageB(0, 1, 0, 0); stageB(0, 1, 1, 0);
    stageA(1, 0, 64); stageA(1, 2, 64);
    stageB(1, 0, 0, 64); stageB(1, 0, 1, 64);
    asm volatile("s_waitcnt vmcnt(4)" ::: "memory");
    __builtin_amdgcn_s_barrier();

    bf16x8 af[4][2];   // A frags for current mh, cached across nh phases
    bf16x8 bff[2][2];  // B frags for current phase

    for (int t = 0; t < NT; ++t) {
        const int cur = t & 1;
        const int kt1 = (t + 1) * 64, kt2 = (t + 2) * 64;
        const u16* Acur = As[cur];
        const u16* Bcur = Bs[cur];
        #pragma unroll
        for (int p = 0; p < 4; ++p) {
            const int mh = p >> 1, nh = p & 1;
            // ---- ds-load fragments ----
            if (nh == 0) {
                #pragma unroll
                for (int mi2 = 0; mi2 < 4; mi2++) {
                    int row = wr * 128 + (mh * 4 + mi2) * 16 + lr;
                    #pragma unroll
                    for (int ks = 0; ks < 2; ks++) {
                        int ch = (ks * 4 + lg) ^ (row & 7);
                        af[mi2][ks] = *(const bf16x8*)(Acur + row * 64 + ch * 8);
                    }
                }
            }
            #pragma unroll
            for (int ni2 = 0; ni2 < 2; ni2++) {
                int row = wc * 64 + (nh * 2 + ni2) * 16 + lr;
                #pragma unroll
                for (int ks = 0; ks < 2; ks++) {
                    int ch = (ks * 4 + lg) ^ (row & 7);
                    bff[ni2][ks] = *(const bf16x8*)(Bcur + row * 64 + ch * 8);
                }
            }
            // ---- stage prefetch (into regions freed by the previous phase) ----
            if (p == 0 && t + 1 < NT) { stageA(cur ^ 1, 1, kt1); stageA(cur ^ 1, 3, kt1); }
            if (p == 1 && t + 1 < NT) { stageB(cur ^ 1, 1, 0, kt1); stageB(cur ^ 1, 1, 1, kt1); }
            if (p == 2 && t + 2 < NT) { stageA(cur, 0, kt2); stageA(cur, 2, kt2); }
            if (p == 3 && t + 2 < NT) { stageB(cur, 0, 0, kt2); stageB(cur, 0, 1, kt2); }

            __builtin_amdgcn_s_barrier();
            asm volatile("s_waitcnt lgkmcnt(0)" ::: "memory");
            __builtin_amdgcn_sched_barrier(0);
            __builtin_amdgcn_s_setprio(1);
            #pragma unroll
            for (int mi2 = 0; mi2 < 4; mi2++)
                #pragma unroll
                for (int ni2 = 0; ni2 < 2; ni2++)
                    #pragma unroll
                    for (int ks = 0; ks < 2; ks++)
                        acc[mh * 4 + mi2][nh * 2 + ni2] =
                            __builtin_amdgcn_mfma_f32_16x16x32_bf16(
                                af[mi2][ks], bff[ni2][ks],
                                acc[mh * 4 + mi2][nh * 2 + ni2], 0, 0, 0);
            __builtin_amdgcn_s_setprio(0);
            if (p == 3) {
                if (t < NT - 2)
                    asm volatile("s_waitcnt vmcnt(4)" ::: "memory");
                else if (t == NT - 2)
                    asm volatile("s_waitcnt vmcnt(0)" ::: "memory");
            }
            __builtin_amdgcn_s_barrier();
        }
    }

    // epilogue
    #pragma unroll
    for (int mi = 0; mi < 8; mi++) {
        #pragma unroll
        for (int ni = 0; ni < 4; ni++) {
            #pragma unroll
            for (int r = 0; r < 4; r++) {
                int gm = m0 + wr * 128 + mi * 16 + lg * 4 + r;
                int gn = n0 + wc * 64 + ni * 16 + lr;
                Cbf[(size_t)gm * ldc + gn] = f2bf(acc[mi][ni][r]);
            }
        }
    }
}

// ---------------- q_summary ----------------
__global__ __launch_bounds__(256) void qsum_kernel(const u16* __restrict__ q_bf,
                                                   float* __restrict__ qsum) {
    int bh = blockIdx.x, b = bh >> 4, h = bh & 15;
    int tid = threadIdx.x, d = tid & 63, c = tid >> 6;
    const u16* base = q_bf + ((size_t)b * 2048 + c) * 1024 + h * 64 + d;
    float acc = 0.f;
    for (int qi = c; qi < 2048; qi += 4) { acc += bf2f(*base); base += 4 * 1024; }
    __shared__ float red[256];
    red[tid] = acc;
    __syncthreads();
    if (tid < 64)
        qsum[bh * 64 + tid] = (red[tid] + red[tid + 64] + red[tid + 128] + red[tid + 192]) * (1.f / 2048.f);
}

// ---------------- selection scores ----------------
__global__ __launch_bounds__(256) void score_kernel(const u16* __restrict__ kv_bf,
                                                    const float* __restrict__ qsum,
                                                    float* __restrict__ score) {
    int bh = blockIdx.y, b = bh >> 4, h = bh & 15;
    __shared__ float qs[64];
    if (threadIdx.x < 64) qs[threadIdx.x] = qsum[bh * 64 + threadIdx.x];
    __syncthreads();
    int kv = blockIdx.x * 256 + threadIdx.x;
    const u16* kr = kv_bf + ((size_t)(b * 16384 + kv)) * 2048 + h * 64;
    float acc = 0.f;
    #pragma unroll
    for (int c = 0; c < 8; c++) {
        uint4 u = *(const uint4*)(kr + c * 8);
        const u16* p = (const u16*)&u;
        #pragma unroll
        for (int j = 0; j < 8; j++) acc += bf2f(p[j]) * qs[c * 8 + j];
    }
    score[(size_t)bh * 16384 + kv] = acc * 0.125f;
}

// ---------------- radix top-2048 select per (b,h) ----------------
__global__ __launch_bounds__(256) void select_kernel(const float* __restrict__ score,
                                                     int* __restrict__ sel_idx) {
    int bh = blockIdx.x;
    const float* sc = score + (size_t)bh * 16384;
    __shared__ int hist[256];
    __shared__ int bc[4];
    int tid = threadIdx.x;
    if (tid == 0) { bc[0] = 0; bc[1] = 2048; bc[2] = 0; bc[3] = 0; }
    __syncthreads();
    for (int shift = 24; shift >= 0; shift -= 8) {
        hist[tid] = 0;
        __syncthreads();
        unsigned int prefix = (unsigned int)bc[0];
        unsigned int hi_mask = (shift == 24) ? 0u : (0xFFFFFFFFu << (shift + 8));
        for (int i = tid; i < 16384; i += 256) {
            unsigned int b = __float_as_uint(sc[i]);
            unsigned int ui = (b & 0x80000000u) ? ~b : (b | 0x80000000u);
            if ((ui & hi_mask) == (prefix & hi_mask))
                atomicAdd(&hist[(ui >> shift) & 0xff], 1);
        }
        __syncthreads();
        if (tid == 0) {
            int want = bc[1], acc = 0, d = 0;
            for (int dd = 255; dd >= 0; dd--) {
                acc += hist[dd];
                if (acc >= want) { d = dd; break; }
            }
            bc[1] = want - (acc - hist[d]);
            bc[0] = (int)(prefix | ((unsigned int)d << shift));
        }
        __syncthreads();
    }
    unsigned int uthr = (unsigned int)bc[0];
    int n_eq = bc[1];
    int base_eq = 2048 - n_eq;
    int* out = sel_idx + (size_t)bh * 2048;
    for (int i = tid; i < 16384; i += 256) {
        unsigned int b = __float_as_uint(sc[i]);
        unsigned int ui = (b & 0x80000000u) ? ~b : (b | 0x80000000u);
        if (ui > uthr) {
            int p = atomicAdd(&bc[2], 1);
            out[p] = i;
        } else if (ui == uthr) {
            int p = atomicAdd(&bc[3], 1);
            if (p < n_eq) out[base_eq + p] = i;
        }
    }
}

// ---------------- gather K_sel (chunk-swizzled) + V_selT (transposed, chunk-swizzled) ----
__global__ __launch_bounds__(256) void gather_kv_kernel(const u16* __restrict__ kv_bf,
                                                        const int* __restrict__ sel_idx,
                                                        u16* __restrict__ k_sel,
                                                        u16* __restrict__ v_selT) {
    int bh = blockIdx.y, b = bh >> 4, h = bh & 15;
    int t0 = blockIdx.x * 64, tid = threadIdx.x;
    __shared__ u16 tile[64][72];
    __shared__ int idx[64];
    if (tid < 64) idx[tid] = sel_idx[(size_t)bh * 2048 + t0 + tid];
    __syncthreads();
    int t = tid >> 2, c4 = tid & 3;
    const u16* src = kv_bf + ((size_t)(b * 16384 + idx[t])) * 2048 + h * 64;
    {
        uint4 a0 = *(const uint4*)(src + c4 * 16);
        uint4 a1 = *(const uint4*)(src + c4 * 16 + 8);
        int key = t & 7;
        u16* kd = k_sel + ((size_t)bh * 2048 + t0 + t) * 64;
        *(uint4*)(kd + ((2 * c4) ^ key) * 8) = a0;
        *(uint4*)(kd + ((2 * c4 + 1) ^ key) * 8) = a1;
    }
    {
        const u16* vsrc = src + 1024 + c4 * 16;
        *(uint4*)&tile[t][c4 * 16]     = *(const uint4*)vsrc;
        *(uint4*)&tile[t][c4 * 16 + 8] = *(const uint4*)(vsrc + 8);
    }
    __syncthreads();
    u16* dst = v_selT + (size_t)bh * 64 * 2048;
    #pragma unroll
    for (int rep = 0; rep < 2; rep++) {
        int ch = tid + rep * 256;
        int d = ch >> 3, c = ch & 7;
        union { u16 u[8]; uint4 v; } tmp;
        #pragma unroll
        for (int j = 0; j < 8; j++) tmp.u[j] = tile[c * 8 + j][d];
        *(uint4*)(dst + (size_t)d * 2048 + t0 + ((c ^ (d & 7)) * 8)) = tmp.v;
    }
}

// ---------------- flash attention over compacted selected KV ----------------
__global__ __launch_bounds__(256) void attn_kernel(
    const u16* __restrict__ q_bf, const u16* __restrict__ k_sel,
    const u16* __restrict__ v_selT, u16* __restrict__ attn_out) {
    const int bh = blockIdx.y, b = bh >> 4, h = bh & 15;
    const int q0 = blockIdx.x * 64;
    const int tid = threadIdx.x, w = tid >> 6, l = tid & 63;
    const int lr = l & 15, lg = l >> 4;
    const int lk = lr & 7;
    const float SC = 0.18033688011f;   // 0.125 * log2(e)
    const float THR = 11.0f;

    __shared__ u16 k_lds[64 * 64];
    __shared__ u16 vt_lds[64 * 64];
    __shared__ __bf16 p_lds[4][16][72];

    const u16* qb = q_bf + ((size_t)b * 2048 + q0 + w * 16 + lr) * 1024 + h * 64;
    bf16x8 qf0 = *(const bf16x8*)(qb + lg * 8);
    bf16x8 qf1 = *(const bf16x8*)(qb + 32 + lg * 8);

    const f32x4 fz = {0.f, 0.f, 0.f, 0.f};
    f32x4 o[4];
    #pragma unroll
    for (int f = 0; f < 4; f++) o[f] = fz;
    float mm[4] = {-1e30f, -1e30f, -1e30f, -1e30f};
    float l_run[4] = {0.f, 0.f, 0.f, 0.f};

    const u16* kb  = k_sel + (size_t)bh * 2048 * 64;
    const u16* vtb = v_selT + (size_t)bh * 64 * 2048;

    #pragma unroll 1
    for (int it = 0; it < 32; ++it) {
        const int t0 = it * 64;
        const u16* ksrc = kb + (size_t)(t0 + w * 16) * 64 + (size_t)l * 8;
        glds16(ksrc,       k_lds + (w * 16) * 64);
        glds16(ksrc + 512, k_lds + (w * 16 + 8) * 64);
        const u16* vsrc = vtb + (size_t)(w * 16 + (l >> 3)) * 2048 + t0 + (l & 7) * 8;
        glds16(vsrc,            vt_lds + (w * 16) * 64);
        glds16(vsrc + 8 * 2048, vt_lds + (w * 16 + 8) * 64);
        __syncthreads();

        f32x4 s[4];
        #pragma unroll
        for (int c = 0; c < 4; c++) s[c] = fz;
        #pragma unroll
        for (int c = 0; c < 4; c++) {
            const u16* krow = k_lds + (c * 16 + lr) * 64;
            bf16x8 kf0 = *(const bf16x8*)(krow + (lg ^ lk) * 8);
            s[c] = __builtin_amdgcn_mfma_f32_16x16x32_bf16(qf0, kf0, s[c], 0, 0, 0);
            bf16x8 kf1 = *(const bf16x8*)(krow + (((4 + lg) ^ lk)) * 8);
            s[c] = __builtin_amdgcn_mfma_f32_16x16x32_bf16(qf1, kf1, s[c], 0, 0, 0);
        }

        float mx[4];
        #pragma unroll
        for (int r = 0; r < 4; r++) {
            float m0 = fmaxf(fmaxf(s[0][r], s[1][r]), fmaxf(s[2][r], s[3][r]));
            m0 = fmaxf(m0, __shfl_xor(m0, 1));
            m0 = fmaxf(m0, __shfl_xor(m0, 2));
            m0 = fmaxf(m0, __shfl_xor(m0, 4));
            m0 = fmaxf(m0, __shfl_xor(m0, 8));
            mx[r] = m0 * SC;
        }
        bool need = false;
        #pragma unroll
        for (int r = 0; r < 4; r++) need = need || (mx[r] > mm[r] + THR);
        if (__any(need)) {
            #pragma unroll
            for (int r = 0; r < 4; r++) {
                float mn = fmaxf(mm[r], mx[r]);
                float al = __builtin_amdgcn_exp2f(mm[r] - mn);
                mm[r] = mn;
                l_run[r] *= al;
                #pragma unroll
                for (int f = 0; f < 4; f++) o[f][r] *= al;
            }
        }
        float rs[4] = {0.f, 0.f, 0.f, 0.f};
        #pragma unroll
        for (int c = 0; c < 4; c++) {
            #pragma unroll
            for (int r = 0; r < 4; r++) {
                float p = __builtin_amdgcn_exp2f(__builtin_fmaf(s[c][r], SC, -mm[r]));
                rs[r] += p;
                p_lds[w][lg * 4 + r][c * 16 + lr] = (__bf16)p;
            }
        }
        #pragma unroll
        for (int r = 0; r < 4; r++) {
            rs[r] += __shfl_xor(rs[r], 1);
            rs[r] += __shfl_xor(rs[r], 2);
            rs[r] += __shfl_xor(rs[r], 4);
            rs[r] += __shfl_xor(rs[r], 8);
            l_run[r] += rs[r];
        }

        #pragma unroll
        for (int kk = 0; kk < 2; kk++) {
            bf16x8 ap = *(const bf16x8*)(&p_lds[w][lr][kk * 32 + lg * 8]);
            #pragma unroll
            for (int f = 0; f < 4; f++) {
                const u16* vrow = vt_lds + (f * 16 + lr) * 64;
                bf16x8 bv = *(const bf16x8*)(vrow + (((kk * 4 + lg) ^ lk)) * 8);
                o[f] = __builtin_amdgcn_mfma_f32_16x16x32_bf16(ap, bv, o[f], 0, 0, 0);
            }
        }
        __syncthreads();
    }

    float invl[4];
    #pragma unroll
    for (int r = 0; r < 4; r++) invl[r] = 1.f / l_run[r];
    u16* ob = attn_out + ((size_t)b * 2048 + q0 + w * 16 + lg * 4) * 1024 + h * 64 + lr;
    #pragma unroll
    for (int f = 0; f < 4; f++) {
        #pragma unroll
        for (int r = 0; r < 4; r++) {
            __bf16 hv = (__bf16)(o[f][r] * invl[r]);
            ob[(size_t)r * 1024 + f * 16] = *(u16*)&hv;
        }
    }
}

// ---------------- launcher ----------------
extern "C" void kernel_launch(void* const* d_in, const int* in_sizes, int n_in,
                              void* d_out, int out_size, void* d_ws, size_t ws_size,
                              hipStream_t stream) {
    const float* hidden = (const float*)d_in[0];
    const float* enc    = (const float*)d_in[1];
    const float* Wq = (const float*)d_in[2];
    const float* Wk = (const float*)d_in[3];
    const float* Wv = (const float*)d_in[4];
    const float* Wo = (const float*)d_in[5];
    const float* bo = (const float*)d_in[6];
    const float* Wg = (const float*)d_in[7];
    const float* bg = (const float*)d_in[8];
    float* out = (float*)d_out;

    char* ws = (char*)d_ws;
    size_t off = 0;
    auto alloc = [&](size_t bytes) -> char* {
        char* p = ws + off;
        off += (bytes + 255) & ~(size_t)255;
        return p;
    };
    u16* hbf   = (u16*)alloc(4096ull * 1024 * 2);
    u16* ebf   = (u16*)alloc(32768ull * 1024 * 2);
    u16* WqT   = (u16*)alloc(1024ull * 1024 * 2);
    u16* WkvT  = (u16*)alloc(2048ull * 1024 * 2);
    u16* WgT   = (u16*)alloc(1024ull * 1024 * 2);
    u16* WoT   = (u16*)alloc(1024ull * 1024 * 2);
    u16* q_bf  = (u16*)alloc(4096ull * 1024 * 2);
    u16* kvbf  = (u16*)alloc(32768ull * 2048 * 2);
    float* qsum = (float*)alloc(32ull * 64 * 4);
    float* scor = (float*)alloc(32ull * 16384 * 4);
    int* sel    = (int*)alloc(32ull * 2048 * 4);
    u16* ksel   = (u16*)alloc(32ull * 2048 * 64 * 2);
    u16* vT     = (u16*)alloc(32ull * 64 * 2048 * 2);
    u16* attn   = (u16*)alloc(4096ull * 1024 * 2);
    u16* gate   = (u16*)alloc(4096ull * 1024 * 2);
    (void)ws_size; (void)in_sizes; (void)n_in; (void)out_size;

    cast_bf16_kernel<<<4096, 256, 0, stream>>>(hidden, hbf, 1048576);
    cast_bf16_kernel<<<32768, 256, 0, stream>>>(enc, ebf, 8388608);
    transpose_cast_kernel<<<dim3(32, 32, 5), dim3(32, 8), 0, stream>>>(
        Wq, Wk, Wv, Wg, Wo, WqT, WkvT, WgT, WoT);

    gemm_bf16<0><<<dim3(8, 32), 256, 0, stream>>>(hbf, WqT, 1024, q_bf, nullptr, nullptr, nullptr, nullptr);
    gemm256_bf16<<<dim3(8, 128), 512, 0, stream>>>(ebf, WkvT, 2048, kvbf);

    qsum_kernel<<<32, 256, 0, stream>>>(q_bf, qsum);
    score_kernel<<<dim3(64, 32), 256, 0, stream>>>(kvbf, qsum, scor);
    select_kernel<<<32, 256, 0, stream>>>(scor, sel);
    gather_kv_kernel<<<dim3(32, 32), 256, 0, stream>>>(kvbf, sel, ksel, vT);

    attn_kernel<<<dim3(32, 32), 256, 0, stream>>>(q_bf, ksel, vT, attn);

    gemm_bf16<2><<<dim3(8, 32), 256, 0, stream>>>(attn, WgT, 1024, gate, bg, attn, nullptr, nullptr);
    gemm_bf16<3><<<dim3(8, 32), 256, 0, stream>>>(gate, WoT, 1024, nullptr, bo, nullptr, hidden, out);
}

// Round 4
// 395.962 us; speedup vs baseline: 1.5423x; 1.5423x over previous
//
#include <hip/hip_runtime.h>
#include <hip/hip_bf16.h>

typedef unsigned short u16;
typedef __bf16 bf16x8 __attribute__((ext_vector_type(8)));
typedef float f32x4 __attribute__((ext_vector_type(4)));

__device__ __forceinline__ u16 f2bf(float f) {
    union { float f; unsigned int u; } v; v.f = f;
    unsigned int u = v.u;
    unsigned int r = (u + 0x7fffu + ((u >> 16) & 1u)) >> 16;
    return (u16)r;
}
__device__ __forceinline__ float bf2f(u16 b) {
    union { unsigned int u; float f; } v; v.u = ((unsigned int)b) << 16;
    return v.f;
}

__device__ __forceinline__ void glds16(const u16* g, u16* l) {
    __builtin_amdgcn_global_load_lds(
        (__attribute__((address_space(1))) void*)(g),
        (__attribute__((address_space(3))) void*)(l), 16, 0, 0);
}

// ---------------- cast fp32 -> bf16 (vectorized) ----------------
__global__ __launch_bounds__(256) void cast_bf16_kernel(const float* __restrict__ src,
                                                        u16* __restrict__ dst, int n4) {
    int i = blockIdx.x * 256 + threadIdx.x;
    if (i >= n4) return;
    float4 v = ((const float4*)src)[i];
    ushort4 o;
    o.x = f2bf(v.x); o.y = f2bf(v.y); o.z = f2bf(v.z); o.w = f2bf(v.w);
    ((ushort4*)dst)[i] = o;
}

// ---------------- transpose+cast weights: WT[n][k] = W[k][n] ----------------
__global__ __launch_bounds__(256) void transpose_cast_kernel(
    const float* __restrict__ Wq, const float* __restrict__ Wk, const float* __restrict__ Wv,
    const float* __restrict__ Wg, const float* __restrict__ Wo,
    u16* __restrict__ WqT, u16* __restrict__ WkvT, u16* __restrict__ WgT, u16* __restrict__ WoT) {
    __shared__ float tile[32][33];
    const float* src; u16* dst;
    switch (blockIdx.z) {
        case 0: src = Wq; dst = WqT; break;
        case 1: src = Wk; dst = WkvT; break;
        case 2: src = Wv; dst = WkvT + (size_t)1024 * 1024; break;
        case 3: src = Wg; dst = WgT; break;
        default: src = Wo; dst = WoT; break;
    }
    int n0 = blockIdx.x * 32, k0 = blockIdx.y * 32;
    int tx = threadIdx.x, ty = threadIdx.y;   // (32, 8)
    #pragma unroll
    for (int j = 0; j < 4; j++)
        tile[ty + j * 8][tx] = src[(size_t)(k0 + ty + j * 8) * 1024 + n0 + tx];
    __syncthreads();
    #pragma unroll
    for (int j = 0; j < 4; j++)
        dst[(size_t)(n0 + ty + j * 8) * 1024 + k0 + tx] = f2bf(tile[tx][ty + j * 8]);
}

// ---------------- 128^2 bf16 MFMA GEMM (m97 structure) ----------------
template <int EPI>
__global__ __launch_bounds__(256) void gemm_bf16(
    const u16* __restrict__ A, const u16* __restrict__ B, int ldc,
    u16* __restrict__ Cbf, const float* __restrict__ bias,
    const u16* __restrict__ mul_src, const float* __restrict__ add_src,
    float* __restrict__ Cf) {
    constexpr int K = 1024;
    const int tid = threadIdx.x;
    const int w = tid >> 6, l = tid & 63;
    const int lr = l & 15, lg = l >> 4;
    const int wr = w >> 1, wc = w & 1;
    const int m0 = blockIdx.y * 128, n0 = blockIdx.x * 128;

    __shared__ u16 As[128 * 64];
    __shared__ u16 Bs[128 * 64];

    const f32x4 fz = {0.f, 0.f, 0.f, 0.f};
    f32x4 acc[4][4];
    #pragma unroll
    for (int i = 0; i < 4; i++)
        #pragma unroll
        for (int j = 0; j < 4; j++) acc[i][j] = fz;

    const int lane_row = l >> 3;
    const int lane_sl  = l & 7;
    const int src_ch   = lane_sl ^ lane_row;
    const u16* Ab = A + (size_t)(m0 + w * 32 + lane_row) * K + src_ch * 8;
    const u16* Bb = B + (size_t)(n0 + w * 32 + lane_row) * K + src_ch * 8;

    for (int kt = 0; kt < K; kt += 64) {
        __syncthreads();
        #pragma unroll
        for (int j = 0; j < 4; j++) {
            glds16(Ab + (size_t)j * 8 * K + kt, As + (w * 32 + j * 8) * 64);
            glds16(Bb + (size_t)j * 8 * K + kt, Bs + (w * 32 + j * 8) * 64);
        }
        __syncthreads();
        #pragma unroll
        for (int kk = 0; kk < 2; kk++) {
            bf16x8 af[4], bfr[4];
            #pragma unroll
            for (int mi = 0; mi < 4; mi++) {
                int row = wr * 64 + mi * 16 + lr;
                int ch = (kk * 4 + lg) ^ (row & 7);
                af[mi] = *(const bf16x8*)(As + row * 64 + ch * 8);
            }
            #pragma unroll
            for (int ni = 0; ni < 4; ni++) {
                int row = wc * 64 + ni * 16 + lr;
                int ch = (kk * 4 + lg) ^ (row & 7);
                bfr[ni] = *(const bf16x8*)(Bs + row * 64 + ch * 8);
            }
            #pragma unroll
            for (int mi = 0; mi < 4; mi++)
                #pragma unroll
                for (int ni = 0; ni < 4; ni++)
                    acc[mi][ni] = __builtin_amdgcn_mfma_f32_16x16x32_bf16(
                        af[mi], bfr[ni], acc[mi][ni], 0, 0, 0);
        }
    }

    #pragma unroll
    for (int mi = 0; mi < 4; mi++) {
        #pragma unroll
        for (int ni = 0; ni < 4; ni++) {
            #pragma unroll
            for (int r = 0; r < 4; r++) {
                int gm = m0 + wr * 64 + mi * 16 + lg * 4 + r;
                int gn = n0 + wc * 64 + ni * 16 + lr;
                float v = acc[mi][ni][r];
                if (EPI == 0) {
                    Cbf[(size_t)gm * ldc + gn] = f2bf(v);
                } else if (EPI == 2) {
                    float g = v + bias[gn];
                    float a = bf2f(mul_src[(size_t)gm * ldc + gn]);
                    float sg = 1.f / (1.f + __expf(-g));
                    Cbf[(size_t)gm * ldc + gn] = f2bf(a * sg);
                } else {
                    Cf[(size_t)gm * ldc + gn] = v + bias[gn] + add_src[(size_t)gm * ldc + gn];
                }
            }
        }
    }
}

// ---------------- hmean: mean over Q of hidden (fp32) ----------------
__global__ __launch_bounds__(256) void hmean_kernel(const float* __restrict__ hidden,
                                                    float* __restrict__ hm) {
    int b = blockIdx.y, c0 = blockIdx.x * 128;
    int tid = threadIdx.x, g = tid >> 5, lane = tid & 31;
    const float4* src = (const float4*)(hidden + (size_t)(b * 2048 + g) * 1024 + c0) + lane;
    float4 acc = {0.f, 0.f, 0.f, 0.f};
    for (int r = g; r < 2048; r += 8) {
        float4 v = *src;
        acc.x += v.x; acc.y += v.y; acc.z += v.z; acc.w += v.w;
        src += 2048;   // 8 rows * 256 float4
    }
    __shared__ float4 red[8][32];
    red[g][lane] = acc;
    __syncthreads();
    if (g == 0) {
        float4 s = red[0][lane];
        #pragma unroll
        for (int i = 1; i < 8; i++) {
            s.x += red[i][lane].x; s.y += red[i][lane].y;
            s.z += red[i][lane].z; s.w += red[i][lane].w;
        }
        const float inv = 1.f / 2048.f;
        s.x *= inv; s.y *= inv; s.z *= inv; s.w *= inv;
        ((float4*)(hm + (size_t)b * 1024 + c0))[lane] = s;
    }
}

// ---------------- qz: qsum = hmean @ Wq_h ; z = qsum @ Wk_h^T (per bh) ----------------
__global__ __launch_bounds__(256) void qz_kernel(const float* __restrict__ hm,
                                                 const u16* __restrict__ WqT,
                                                 const u16* __restrict__ WkT,
                                                 u16* __restrict__ z_bf) {
    int bh = blockIdx.x, b = bh >> 4, h = bh & 15;
    int tid = threadIdx.x;
    __shared__ float hm_l[1024];
    __shared__ float qs_l[64];
    __shared__ float red[256];
    ((float4*)hm_l)[tid] = ((const float4*)(hm + (size_t)b * 1024))[tid];
    __syncthreads();
    {   // qsum[d] = sum_c hm[c] * WqT[h*64+d][c]
        int d = tid >> 2, q = tid & 3;
        const u16* wq = WqT + (size_t)(h * 64 + d) * 1024 + q * 256;
        float a = 0.f;
        for (int i = 0; i < 256; i += 8) {
            uint4 u = *(const uint4*)(wq + i);
            const u16* p = (const u16*)&u;
            #pragma unroll
            for (int j = 0; j < 8; j++) a += bf2f(p[j]) * hm_l[q * 256 + i + j];
        }
        red[tid] = a;
    }
    __syncthreads();
    if (tid < 64)
        qs_l[tid] = red[tid * 4] + red[tid * 4 + 1] + red[tid * 4 + 2] + red[tid * 4 + 3];
    __syncthreads();
    {   // z[c] = sum_d qs[d] * WkT[h*64+d][c]
        float z0 = 0.f, z1 = 0.f, z2 = 0.f, z3 = 0.f;
        for (int d = 0; d < 64; d++) {
            float qs = qs_l[d];
            const u16* wk = WkT + (size_t)(h * 64 + d) * 1024 + tid * 4;
            uint2 u = *(const uint2*)wk;
            const u16* p = (const u16*)&u;
            z0 += qs * bf2f(p[0]); z1 += qs * bf2f(p[1]);
            z2 += qs * bf2f(p[2]); z3 += qs * bf2f(p[3]);
        }
        ushort4 o;
        o.x = f2bf(z0); o.y = f2bf(z1); o.z = f2bf(z2); o.w = f2bf(z3);
        *(ushort4*)(z_bf + (size_t)bh * 1024 + tid * 4) = o;
    }
}

// ---------------- score via MFMA: score[b*16+h][kv] = z[bh] . enc[kv] ----------------
__global__ __launch_bounds__(256) void score_mfma_kernel(const u16* __restrict__ ebf,
                                                         const u16* __restrict__ z_bf,
                                                         float* __restrict__ score) {
    const int b = blockIdx.y, kv0 = blockIdx.x * 256;
    const int tid = threadIdx.x, w = tid >> 6, l = tid & 63;
    const int lr = l & 15, lg = l >> 4;
    __shared__ u16 z_lds[16 * 1024];
    __shared__ u16 e_lds[256 * 64];
    {   // stage all 16 heads' z, chunk-swizzled
        int row = tid >> 4, cg = tid & 15;
        const u16* src = z_bf + (size_t)(b * 16 + row) * 1024 + cg * 64;
        #pragma unroll
        for (int i = 0; i < 8; i++) {
            uint4 u = *(const uint4*)(src + i * 8);
            int ch = cg * 8 + i;
            *(uint4*)(z_lds + row * 1024 + (ch ^ (row & 7)) * 8) = u;
        }
    }
    const int lane_row = l >> 3, src_ch = (l & 7) ^ lane_row;
    const f32x4 fz = {0.f, 0.f, 0.f, 0.f};
    f32x4 acc[4];
    #pragma unroll
    for (int ni = 0; ni < 4; ni++) acc[ni] = fz;

    for (int kt = 0; kt < 1024; kt += 64) {
        __syncthreads();
        #pragma unroll
        for (int j = 0; j < 8; j++) {
            const u16* src = ebf + (size_t)(b * 16384 + kv0 + w * 64 + j * 8 + lane_row) * 1024 + kt + src_ch * 8;
            glds16(src, e_lds + (w * 64 + j * 8) * 64);
        }
        __syncthreads();
        #pragma unroll
        for (int ks = 0; ks < 2; ks++) {
            int chg = (kt >> 3) + ks * 4 + lg;
            bf16x8 af = *(const bf16x8*)(z_lds + lr * 1024 + (chg ^ (lr & 7)) * 8);
            #pragma unroll
            for (int ni = 0; ni < 4; ni++) {
                int row = w * 64 + ni * 16 + lr;
                bf16x8 bf_ = *(const bf16x8*)(e_lds + row * 64 + (((ks * 4 + lg) ^ (lr & 7))) * 8);
                acc[ni] = __builtin_amdgcn_mfma_f32_16x16x32_bf16(af, bf_, acc[ni], 0, 0, 0);
            }
        }
    }
    #pragma unroll
    for (int ni = 0; ni < 4; ni++)
        #pragma unroll
        for (int r = 0; r < 4; r++)
            score[(size_t)(b * 16 + lg * 4 + r) * 16384 + kv0 + w * 64 + ni * 16 + lr] = acc[ni][r];
}

// ---------------- radix top-2048 select per (b,h) ----------------
__global__ __launch_bounds__(256) void select_kernel(const float* __restrict__ score,
                                                     int* __restrict__ sel_idx) {
    int bh = blockIdx.x;
    const float* sc = score + (size_t)bh * 16384;
    __shared__ int hist[256];
    __shared__ int bc[4];
    int tid = threadIdx.x;
    if (tid == 0) { bc[0] = 0; bc[1] = 2048; bc[2] = 0; bc[3] = 0; }
    __syncthreads();
    for (int shift = 24; shift >= 0; shift -= 8) {
        hist[tid] = 0;
        __syncthreads();
        unsigned int prefix = (unsigned int)bc[0];
        unsigned int hi_mask = (shift == 24) ? 0u : (0xFFFFFFFFu << (shift + 8));
        for (int i = tid; i < 16384; i += 256) {
            unsigned int b = __float_as_uint(sc[i]);
            unsigned int ui = (b & 0x80000000u) ? ~b : (b | 0x80000000u);
            if ((ui & hi_mask) == (prefix & hi_mask))
                atomicAdd(&hist[(ui >> shift) & 0xff], 1);
        }
        __syncthreads();
        if (tid == 0) {
            int want = bc[1], acc = 0, d = 0;
            for (int dd = 255; dd >= 0; dd--) {
                acc += hist[dd];
                if (acc >= want) { d = dd; break; }
            }
            bc[1] = want - (acc - hist[d]);
            bc[0] = (int)(prefix | ((unsigned int)d << shift));
        }
        __syncthreads();
    }
    unsigned int uthr = (unsigned int)bc[0];
    int n_eq = bc[1];
    int base_eq = 2048 - n_eq;
    int* out = sel_idx + (size_t)bh * 2048;
    for (int i = tid; i < 16384; i += 256) {
        unsigned int b = __float_as_uint(sc[i]);
        unsigned int ui = (b & 0x80000000u) ? ~b : (b | 0x80000000u);
        if (ui > uthr) {
            int p = atomicAdd(&bc[2], 1);
            out[p] = i;
        } else if (ui == uthr) {
            int p = atomicAdd(&bc[3], 1);
            if (p < n_eq) out[base_eq + p] = i;
        }
    }
}

// ---------------- selected projection: K_sel[t][d] and V_selT[d][t] (chunk-swizzled) ----
// Per (bh, 128-t tile): K_sel = encG @ WkT_h^T,  V_selT = WvT_h @ encG^T.
__global__ __launch_bounds__(256) void selproj_kernel(const u16* __restrict__ ebf,
                                                      const u16* __restrict__ WkvT,
                                                      const int* __restrict__ sel_idx,
                                                      u16* __restrict__ k_sel,
                                                      u16* __restrict__ v_selT) {
    const int bh = blockIdx.y, b = bh >> 4, h = bh & 15;
    const int t0 = blockIdx.x * 128;
    const int tid = threadIdx.x, w = tid >> 6, l = tid & 63;
    const int lr = l & 15, lg = l >> 4;
    const int lane_row = l >> 3, src_ch = (l & 7) ^ lane_row;

    __shared__ u16 e_lds[128 * 64];
    __shared__ u16 w_lds[128 * 64];   // rows 0-63: WkT_h, rows 64-127: WvT_h

    int encrow[4], wrow[4];
    #pragma unroll
    for (int j = 0; j < 4; j++) {
        int t = t0 + w * 32 + j * 8 + lane_row;
        encrow[j] = b * 16384 + sel_idx[(size_t)bh * 2048 + t];
        int r = w * 32 + j * 8 + lane_row;
        wrow[j] = (r < 64) ? (h * 64 + r) : (1024 + h * 64 + (r & 63));
    }

    const f32x4 fz = {0.f, 0.f, 0.f, 0.f};
    f32x4 acc_k[2][4], acc_v[8];
    #pragma unroll
    for (int i = 0; i < 2; i++)
        #pragma unroll
        for (int j = 0; j < 4; j++) acc_k[i][j] = fz;
    #pragma unroll
    for (int i = 0; i < 8; i++) acc_v[i] = fz;

    for (int kt = 0; kt < 1024; kt += 64) {
        __syncthreads();
        #pragma unroll
        for (int j = 0; j < 4; j++) {
            glds16(ebf + (size_t)encrow[j] * 1024 + kt + src_ch * 8, e_lds + (w * 32 + j * 8) * 64);
            glds16(WkvT + (size_t)wrow[j] * 1024 + kt + src_ch * 8, w_lds + (w * 32 + j * 8) * 64);
        }
        __syncthreads();
        #pragma unroll
        for (int ks = 0; ks < 2; ks++) {
            bf16x8 ae[2];
            #pragma unroll
            for (int mi = 0; mi < 2; mi++) {
                int row = w * 32 + mi * 16 + lr;
                ae[mi] = *(const bf16x8*)(e_lds + row * 64 + (((ks * 4 + lg) ^ (row & 7))) * 8);
            }
            bf16x8 aw;
            {
                int row = 64 + w * 16 + lr;
                aw = *(const bf16x8*)(w_lds + row * 64 + (((ks * 4 + lg) ^ (row & 7))) * 8);
            }
            #pragma unroll
            for (int ni = 0; ni < 4; ni++) {
                int row = ni * 16 + lr;
                bf16x8 bw = *(const bf16x8*)(w_lds + row * 64 + (((ks * 4 + lg) ^ (row & 7))) * 8);
                acc_k[0][ni] = __builtin_amdgcn_mfma_f32_16x16x32_bf16(ae[0], bw, acc_k[0][ni], 0, 0, 0);
                acc_k[1][ni] = __builtin_amdgcn_mfma_f32_16x16x32_bf16(ae[1], bw, acc_k[1][ni], 0, 0, 0);
            }
            #pragma unroll
            for (int ni = 0; ni < 8; ni++) {
                int row = ni * 16 + lr;
                bf16x8 be = *(const bf16x8*)(e_lds + row * 64 + (((ks * 4 + lg) ^ (row & 7))) * 8);
                acc_v[ni] = __builtin_amdgcn_mfma_f32_16x16x32_bf16(aw, be, acc_v[ni], 0, 0, 0);
            }
        }
    }

    // K epilogue: row t, chunk-swizzled by t&7
    u16* kb = k_sel + (size_t)bh * 2048 * 64;
    #pragma unroll
    for (int mi = 0; mi < 2; mi++)
        #pragma unroll
        for (int ni = 0; ni < 4; ni++)
            #pragma unroll
            for (int r = 0; r < 4; r++) {
                int t = t0 + w * 32 + mi * 16 + lg * 4 + r;
                int d = ni * 16 + lr;
                kb[(size_t)t * 64 + (((d >> 3) ^ (t & 7)) * 8) + (d & 7)] = f2bf(acc_k[mi][ni][r]);
            }
    // V epilogue: row d, 64-blocked t with chunk-swizzle by d&7
    u16* vb = v_selT + (size_t)bh * 64 * 2048;
    #pragma unroll
    for (int ni = 0; ni < 8; ni++)
        #pragma unroll
        for (int r = 0; r < 4; r++) {
            int d = w * 16 + lg * 4 + r;
            int t = t0 + ni * 16 + lr;
            int tl = t & 63;
            vb[(size_t)d * 2048 + (t & ~63) + ((((tl >> 3) ^ (d & 7))) * 8) + (tl & 7)] =
                f2bf(acc_v[ni][r]);
        }
}

// ---------------- flash attention over compacted selected KV ----------------
__global__ __launch_bounds__(256) void attn_kernel(
    const u16* __restrict__ q_bf, const u16* __restrict__ k_sel,
    const u16* __restrict__ v_selT, u16* __restrict__ attn_out) {
    const int bh = blockIdx.y, b = bh >> 4, h = bh & 15;
    const int q0 = blockIdx.x * 64;
    const int tid = threadIdx.x, w = tid >> 6, l = tid & 63;
    const int lr = l & 15, lg = l >> 4;
    const int lk = lr & 7;
    const float SC = 0.18033688011f;   // 0.125 * log2(e)
    const float THR = 11.0f;

    __shared__ u16 k_lds[64 * 64];
    __shared__ u16 vt_lds[64 * 64];
    __shared__ __bf16 p_lds[4][16][72];

    const u16* qb = q_bf + ((size_t)b * 2048 + q0 + w * 16 + lr) * 1024 + h * 64;
    bf16x8 qf0 = *(const bf16x8*)(qb + lg * 8);
    bf16x8 qf1 = *(const bf16x8*)(qb + 32 + lg * 8);

    const f32x4 fz = {0.f, 0.f, 0.f, 0.f};
    f32x4 o[4];
    #pragma unroll
    for (int f = 0; f < 4; f++) o[f] = fz;
    float mm[4] = {-1e30f, -1e30f, -1e30f, -1e30f};
    float l_run[4] = {0.f, 0.f, 0.f, 0.f};

    const u16* kb  = k_sel + (size_t)bh * 2048 * 64;
    const u16* vtb = v_selT + (size_t)bh * 64 * 2048;

    #pragma unroll 1
    for (int it = 0; it < 32; ++it) {
        const int t0 = it * 64;
        const u16* ksrc = kb + (size_t)(t0 + w * 16) * 64 + (size_t)l * 8;
        glds16(ksrc,       k_lds + (w * 16) * 64);
        glds16(ksrc + 512, k_lds + (w * 16 + 8) * 64);
        const u16* vsrc = vtb + (size_t)(w * 16 + (l >> 3)) * 2048 + t0 + (l & 7) * 8;
        glds16(vsrc,            vt_lds + (w * 16) * 64);
        glds16(vsrc + 8 * 2048, vt_lds + (w * 16 + 8) * 64);
        __syncthreads();

        f32x4 s[4];
        #pragma unroll
        for (int c = 0; c < 4; c++) s[c] = fz;
        #pragma unroll
        for (int c = 0; c < 4; c++) {
            const u16* krow = k_lds + (c * 16 + lr) * 64;
            bf16x8 kf0 = *(const bf16x8*)(krow + (lg ^ lk) * 8);
            s[c] = __builtin_amdgcn_mfma_f32_16x16x32_bf16(qf0, kf0, s[c], 0, 0, 0);
            bf16x8 kf1 = *(const bf16x8*)(krow + (((4 + lg) ^ lk)) * 8);
            s[c] = __builtin_amdgcn_mfma_f32_16x16x32_bf16(qf1, kf1, s[c], 0, 0, 0);
        }

        float mx[4];
        #pragma unroll
        for (int r = 0; r < 4; r++) {
            float m0 = fmaxf(fmaxf(s[0][r], s[1][r]), fmaxf(s[2][r], s[3][r]));
            m0 = fmaxf(m0, __shfl_xor(m0, 1));
            m0 = fmaxf(m0, __shfl_xor(m0, 2));
            m0 = fmaxf(m0, __shfl_xor(m0, 4));
            m0 = fmaxf(m0, __shfl_xor(m0, 8));
            mx[r] = m0 * SC;
        }
        bool need = false;
        #pragma unroll
        for (int r = 0; r < 4; r++) need = need || (mx[r] > mm[r] + THR);
        if (__any(need)) {
            #pragma unroll
            for (int r = 0; r < 4; r++) {
                float mn = fmaxf(mm[r], mx[r]);
                float al = __builtin_amdgcn_exp2f(mm[r] - mn);
                mm[r] = mn;
                l_run[r] *= al;
                #pragma unroll
                for (int f = 0; f < 4; f++) o[f][r] *= al;
            }
        }
        float rs[4] = {0.f, 0.f, 0.f, 0.f};
        #pragma unroll
        for (int c = 0; c < 4; c++) {
            #pragma unroll
            for (int r = 0; r < 4; r++) {
                float p = __builtin_amdgcn_exp2f(__builtin_fmaf(s[c][r], SC, -mm[r]));
                rs[r] += p;
                p_lds[w][lg * 4 + r][c * 16 + lr] = (__bf16)p;
            }
        }
        #pragma unroll
        for (int r = 0; r < 4; r++) {
            rs[r] += __shfl_xor(rs[r], 1);
            rs[r] += __shfl_xor(rs[r], 2);
            rs[r] += __shfl_xor(rs[r], 4);
            rs[r] += __shfl_xor(rs[r], 8);
            l_run[r] += rs[r];
        }

        #pragma unroll
        for (int kk = 0; kk < 2; kk++) {
            bf16x8 ap = *(const bf16x8*)(&p_lds[w][lr][kk * 32 + lg * 8]);
            #pragma unroll
            for (int f = 0; f < 4; f++) {
                const u16* vrow = vt_lds + (f * 16 + lr) * 64;
                bf16x8 bv = *(const bf16x8*)(vrow + (((kk * 4 + lg) ^ lk)) * 8);
                o[f] = __builtin_amdgcn_mfma_f32_16x16x32_bf16(ap, bv, o[f], 0, 0, 0);
            }
        }
        __syncthreads();
    }

    float invl[4];
    #pragma unroll
    for (int r = 0; r < 4; r++) invl[r] = 1.f / l_run[r];
    u16* ob = attn_out + ((size_t)b * 2048 + q0 + w * 16 + lg * 4) * 1024 + h * 64 + lr;
    #pragma unroll
    for (int f = 0; f < 4; f++) {
        #pragma unroll
        for (int r = 0; r < 4; r++) {
            __bf16 hv = (__bf16)(o[f][r] * invl[r]);
            ob[(size_t)r * 1024 + f * 16] = *(u16*)&hv;
        }
    }
}

// ---------------- launcher ----------------
extern "C" void kernel_launch(void* const* d_in, const int* in_sizes, int n_in,
                              void* d_out, int out_size, void* d_ws, size_t ws_size,
                              hipStream_t stream) {
    const float* hidden = (const float*)d_in[0];
    const float* enc    = (const float*)d_in[1];
    const float* Wq = (const float*)d_in[2];
    const float* Wk = (const float*)d_in[3];
    const float* Wv = (const float*)d_in[4];
    const float* Wo = (const float*)d_in[5];
    const float* bo = (const float*)d_in[6];
    const float* Wg = (const float*)d_in[7];
    const float* bg = (const float*)d_in[8];
    float* out = (float*)d_out;

    char* ws = (char*)d_ws;
    size_t off = 0;
    auto alloc = [&](size_t bytes) -> char* {
        char* p = ws + off;
        off += (bytes + 255) & ~(size_t)255;
        return p;
    };
    u16* hbf   = (u16*)alloc(4096ull * 1024 * 2);
    u16* ebf   = (u16*)alloc(32768ull * 1024 * 2);
    u16* WqT   = (u16*)alloc(1024ull * 1024 * 2);
    u16* WkvT  = (u16*)alloc(2048ull * 1024 * 2);
    u16* WgT   = (u16*)alloc(1024ull * 1024 * 2);
    u16* WoT   = (u16*)alloc(1024ull * 1024 * 2);
    u16* q_bf  = (u16*)alloc(4096ull * 1024 * 2);
    float* hm  = (float*)alloc(2ull * 1024 * 4);
    u16* z_bf  = (u16*)alloc(32ull * 1024 * 2);
    float* scor = (float*)alloc(32ull * 16384 * 4);
    int* sel    = (int*)alloc(32ull * 2048 * 4);
    u16* ksel   = (u16*)alloc(32ull * 2048 * 64 * 2);
    u16* vT     = (u16*)alloc(32ull * 64 * 2048 * 2);
    u16* attn   = (u16*)alloc(4096ull * 1024 * 2);
    u16* gate   = (u16*)alloc(4096ull * 1024 * 2);
    (void)ws_size; (void)in_sizes; (void)n_in; (void)out_size;

    hmean_kernel<<<dim3(8, 2), 256, 0, stream>>>(hidden, hm);
    cast_bf16_kernel<<<4096, 256, 0, stream>>>(hidden, hbf, 1048576);
    cast_bf16_kernel<<<32768, 256, 0, stream>>>(enc, ebf, 8388608);
    transpose_cast_kernel<<<dim3(32, 32, 5), dim3(32, 8), 0, stream>>>(
        Wq, Wk, Wv, Wg, Wo, WqT, WkvT, WgT, WoT);

    qz_kernel<<<32, 256, 0, stream>>>(hm, WqT, WkvT, z_bf);
    score_mfma_kernel<<<dim3(64, 2), 256, 0, stream>>>(ebf, z_bf, scor);
    select_kernel<<<32, 256, 0, stream>>>(scor, sel);
    selproj_kernel<<<dim3(16, 32), 256, 0, stream>>>(ebf, WkvT, sel, ksel, vT);

    gemm_bf16<0><<<dim3(8, 32), 256, 0, stream>>>(hbf, WqT, 1024, q_bf, nullptr, nullptr, nullptr, nullptr);
    attn_kernel<<<dim3(32, 32), 256, 0, stream>>>(q_bf, ksel, vT, attn);

    gemm_bf16<2><<<dim3(8, 32), 256, 0, stream>>>(attn, WgT, 1024, gate, bg, attn, nullptr, nullptr);
    gemm_bf16<3><<<dim3(8, 32), 256, 0, stream>>>(gate, WoT, 1024, nullptr, bo, nullptr, hidden, out);
}

// Round 5
// 378.115 us; speedup vs baseline: 1.6151x; 1.0472x over previous
//
#include <hip/hip_runtime.h>
#include <hip/hip_bf16.h>

typedef unsigned short u16;
typedef __bf16 bf16x8 __attribute__((ext_vector_type(8)));
typedef float f32x4 __attribute__((ext_vector_type(4)));

__device__ __forceinline__ u16 f2bf(float f) {
    union { float f; unsigned int u; } v; v.f = f;
    unsigned int u = v.u;
    unsigned int r = (u + 0x7fffu + ((u >> 16) & 1u)) >> 16;
    return (u16)r;
}
__device__ __forceinline__ float bf2f(u16 b) {
    union { unsigned int u; float f; } v; v.u = ((unsigned int)b) << 16;
    return v.f;
}

__device__ __forceinline__ void glds16(const u16* g, u16* l) {
    __builtin_amdgcn_global_load_lds(
        (__attribute__((address_space(1))) void*)(g),
        (__attribute__((address_space(3))) void*)(l), 16, 0, 0);
}

// ---------------- cast fp32 -> bf16 (vectorized) ----------------
__global__ __launch_bounds__(256) void cast_bf16_kernel(const float* __restrict__ src,
                                                        u16* __restrict__ dst, int n4) {
    int i = blockIdx.x * 256 + threadIdx.x;
    if (i >= n4) return;
    float4 v = ((const float4*)src)[i];
    ushort4 o;
    o.x = f2bf(v.x); o.y = f2bf(v.y); o.z = f2bf(v.z); o.w = f2bf(v.w);
    ((ushort4*)dst)[i] = o;
}

// ---------------- transpose+cast weights: WT[n][k] = W[k][n] ----------------
__global__ __launch_bounds__(256) void transpose_cast_kernel(
    const float* __restrict__ Wq, const float* __restrict__ Wk, const float* __restrict__ Wv,
    const float* __restrict__ Wg, const float* __restrict__ Wo,
    u16* __restrict__ WqT, u16* __restrict__ WkvT, u16* __restrict__ WgT, u16* __restrict__ WoT) {
    __shared__ float tile[32][33];
    const float* src; u16* dst;
    switch (blockIdx.z) {
        case 0: src = Wq; dst = WqT; break;
        case 1: src = Wk; dst = WkvT; break;
        case 2: src = Wv; dst = WkvT + (size_t)1024 * 1024; break;
        case 3: src = Wg; dst = WgT; break;
        default: src = Wo; dst = WoT; break;
    }
    int n0 = blockIdx.x * 32, k0 = blockIdx.y * 32;
    int tx = threadIdx.x, ty = threadIdx.y;   // (32, 8)
    #pragma unroll
    for (int j = 0; j < 4; j++)
        tile[ty + j * 8][tx] = src[(size_t)(k0 + ty + j * 8) * 1024 + n0 + tx];
    __syncthreads();
    #pragma unroll
    for (int j = 0; j < 4; j++)
        dst[(size_t)(n0 + ty + j * 8) * 1024 + k0 + tx] = f2bf(tile[tx][ty + j * 8]);
}

// ---------------- 128^2 bf16 MFMA GEMM (m97 structure) ----------------
template <int EPI>
__global__ __launch_bounds__(256) void gemm_bf16(
    const u16* __restrict__ A, const u16* __restrict__ B, int ldc,
    u16* __restrict__ Cbf, const float* __restrict__ bias,
    const u16* __restrict__ mul_src, const float* __restrict__ add_src,
    float* __restrict__ Cf) {
    constexpr int K = 1024;
    const int tid = threadIdx.x;
    const int w = tid >> 6, l = tid & 63;
    const int lr = l & 15, lg = l >> 4;
    const int wr = w >> 1, wc = w & 1;
    const int m0 = blockIdx.y * 128, n0 = blockIdx.x * 128;

    __shared__ u16 As[128 * 64];
    __shared__ u16 Bs[128 * 64];

    const f32x4 fz = {0.f, 0.f, 0.f, 0.f};
    f32x4 acc[4][4];
    #pragma unroll
    for (int i = 0; i < 4; i++)
        #pragma unroll
        for (int j = 0; j < 4; j++) acc[i][j] = fz;

    const int lane_row = l >> 3;
    const int lane_sl  = l & 7;
    const int src_ch   = lane_sl ^ lane_row;
    const u16* Ab = A + (size_t)(m0 + w * 32 + lane_row) * K + src_ch * 8;
    const u16* Bb = B + (size_t)(n0 + w * 32 + lane_row) * K + src_ch * 8;

    for (int kt = 0; kt < K; kt += 64) {
        __syncthreads();
        #pragma unroll
        for (int j = 0; j < 4; j++) {
            glds16(Ab + (size_t)j * 8 * K + kt, As + (w * 32 + j * 8) * 64);
            glds16(Bb + (size_t)j * 8 * K + kt, Bs + (w * 32 + j * 8) * 64);
        }
        __syncthreads();
        #pragma unroll
        for (int kk = 0; kk < 2; kk++) {
            bf16x8 af[4], bfr[4];
            #pragma unroll
            for (int mi = 0; mi < 4; mi++) {
                int row = wr * 64 + mi * 16 + lr;
                int ch = (kk * 4 + lg) ^ (row & 7);
                af[mi] = *(const bf16x8*)(As + row * 64 + ch * 8);
            }
            #pragma unroll
            for (int ni = 0; ni < 4; ni++) {
                int row = wc * 64 + ni * 16 + lr;
                int ch = (kk * 4 + lg) ^ (row & 7);
                bfr[ni] = *(const bf16x8*)(Bs + row * 64 + ch * 8);
            }
            #pragma unroll
            for (int mi = 0; mi < 4; mi++)
                #pragma unroll
                for (int ni = 0; ni < 4; ni++)
                    acc[mi][ni] = __builtin_amdgcn_mfma_f32_16x16x32_bf16(
                        af[mi], bfr[ni], acc[mi][ni], 0, 0, 0);
        }
    }

    #pragma unroll
    for (int mi = 0; mi < 4; mi++) {
        #pragma unroll
        for (int ni = 0; ni < 4; ni++) {
            #pragma unroll
            for (int r = 0; r < 4; r++) {
                int gm = m0 + wr * 64 + mi * 16 + lg * 4 + r;
                int gn = n0 + wc * 64 + ni * 16 + lr;
                float v = acc[mi][ni][r];
                if (EPI == 0) {
                    Cbf[(size_t)gm * ldc + gn] = f2bf(v);
                } else if (EPI == 2) {
                    float g = v + bias[gn];
                    float a = bf2f(mul_src[(size_t)gm * ldc + gn]);
                    float sg = 1.f / (1.f + __expf(-g));
                    Cbf[(size_t)gm * ldc + gn] = f2bf(a * sg);
                } else {
                    Cf[(size_t)gm * ldc + gn] = v + bias[gn] + add_src[(size_t)gm * ldc + gn];
                }
            }
        }
    }
}

// ---------------- hidden column-sum, stage 1: 16-row partials ----------------
__global__ __launch_bounds__(256) void hsum1_kernel(const float* __restrict__ hidden,
                                                    float* __restrict__ part) {
    int b = blockIdx.x, chunk = blockIdx.y;   // (2, 128)
    int tid = threadIdx.x;
    const float4* src = (const float4*)(hidden + ((size_t)b * 2048 + chunk * 16) * 1024) + tid;
    float4 acc = {0.f, 0.f, 0.f, 0.f};
    #pragma unroll
    for (int r = 0; r < 16; r++) {
        float4 v = src[r * 256];
        acc.x += v.x; acc.y += v.y; acc.z += v.z; acc.w += v.w;
    }
    ((float4*)(part + ((size_t)b * 128 + chunk) * 1024))[tid] = acc;
}

// ---------------- stage 2: reduce 128 partials -> mean ----------------
__global__ __launch_bounds__(256) void hsum2_kernel(const float* __restrict__ part,
                                                    float* __restrict__ hm) {
    int b = blockIdx.x, tid = threadIdx.x;
    const float4* src = (const float4*)(part + (size_t)b * 128 * 1024) + tid;
    float4 acc = {0.f, 0.f, 0.f, 0.f};
    for (int c = 0; c < 128; c++) {
        float4 v = src[c * 256];
        acc.x += v.x; acc.y += v.y; acc.z += v.z; acc.w += v.w;
    }
    const float inv = 1.f / 2048.f;
    acc.x *= inv; acc.y *= inv; acc.z *= inv; acc.w *= inv;
    ((float4*)(hm + (size_t)b * 1024))[tid] = acc;
}

// ---------------- qz: qsum = hmean @ Wq_h ; z = qsum @ Wk_h^T (per bh) ----------------
__global__ __launch_bounds__(256) void qz_kernel(const float* __restrict__ hm,
                                                 const u16* __restrict__ WqT,
                                                 const u16* __restrict__ WkT,
                                                 u16* __restrict__ z_bf) {
    int bh = blockIdx.x, b = bh >> 4, h = bh & 15;
    int tid = threadIdx.x;
    __shared__ float hm_l[1024];
    __shared__ float qs_l[64];
    __shared__ float red[256];
    ((float4*)hm_l)[tid] = ((const float4*)(hm + (size_t)b * 1024))[tid];
    __syncthreads();
    {
        int d = tid >> 2, q = tid & 3;
        const u16* wq = WqT + (size_t)(h * 64 + d) * 1024 + q * 256;
        float a = 0.f;
        for (int i = 0; i < 256; i += 8) {
            uint4 u = *(const uint4*)(wq + i);
            const u16* p = (const u16*)&u;
            #pragma unroll
            for (int j = 0; j < 8; j++) a += bf2f(p[j]) * hm_l[q * 256 + i + j];
        }
        red[tid] = a;
    }
    __syncthreads();
    if (tid < 64)
        qs_l[tid] = red[tid * 4] + red[tid * 4 + 1] + red[tid * 4 + 2] + red[tid * 4 + 3];
    __syncthreads();
    {
        float z0 = 0.f, z1 = 0.f, z2 = 0.f, z3 = 0.f;
        for (int d = 0; d < 64; d++) {
            float qs = qs_l[d];
            const u16* wk = WkT + (size_t)(h * 64 + d) * 1024 + tid * 4;
            uint2 u = *(const uint2*)wk;
            const u16* p = (const u16*)&u;
            z0 += qs * bf2f(p[0]); z1 += qs * bf2f(p[1]);
            z2 += qs * bf2f(p[2]); z3 += qs * bf2f(p[3]);
        }
        ushort4 o;
        o.x = f2bf(z0); o.y = f2bf(z1); o.z = f2bf(z2); o.w = f2bf(z3);
        *(ushort4*)(z_bf + (size_t)bh * 1024 + tid * 4) = o;
    }
}

// ---------------- score via MFMA: score[b*16+h][kv] = z[bh] . enc[kv] ----------------
__global__ __launch_bounds__(256) void score_mfma_kernel(const u16* __restrict__ ebf,
                                                         const u16* __restrict__ z_bf,
                                                         float* __restrict__ score) {
    const int b = blockIdx.y, kv0 = blockIdx.x * 256;
    const int tid = threadIdx.x, w = tid >> 6, l = tid & 63;
    const int lr = l & 15, lg = l >> 4;
    __shared__ u16 z_lds[16 * 1024];
    __shared__ u16 e_lds[256 * 64];
    {
        int row = tid >> 4, cg = tid & 15;
        const u16* src = z_bf + (size_t)(b * 16 + row) * 1024 + cg * 64;
        #pragma unroll
        for (int i = 0; i < 8; i++) {
            uint4 u = *(const uint4*)(src + i * 8);
            int ch = cg * 8 + i;
            *(uint4*)(z_lds + row * 1024 + (ch ^ (row & 7)) * 8) = u;
        }
    }
    const int lane_row = l >> 3, src_ch = (l & 7) ^ lane_row;
    const f32x4 fz = {0.f, 0.f, 0.f, 0.f};
    f32x4 acc[4];
    #pragma unroll
    for (int ni = 0; ni < 4; ni++) acc[ni] = fz;

    for (int kt = 0; kt < 1024; kt += 64) {
        __syncthreads();
        #pragma unroll
        for (int j = 0; j < 8; j++) {
            const u16* src = ebf + (size_t)(b * 16384 + kv0 + w * 64 + j * 8 + lane_row) * 1024 + kt + src_ch * 8;
            glds16(src, e_lds + (w * 64 + j * 8) * 64);
        }
        __syncthreads();
        #pragma unroll
        for (int ks = 0; ks < 2; ks++) {
            int chg = (kt >> 3) + ks * 4 + lg;
            bf16x8 af = *(const bf16x8*)(z_lds + lr * 1024 + (chg ^ (lr & 7)) * 8);
            #pragma unroll
            for (int ni = 0; ni < 4; ni++) {
                int row = w * 64 + ni * 16 + lr;
                bf16x8 bf_ = *(const bf16x8*)(e_lds + row * 64 + (((ks * 4 + lg) ^ (lr & 7))) * 8);
                acc[ni] = __builtin_amdgcn_mfma_f32_16x16x32_bf16(af, bf_, acc[ni], 0, 0, 0);
            }
        }
    }
    #pragma unroll
    for (int ni = 0; ni < 4; ni++)
        #pragma unroll
        for (int r = 0; r < 4; r++)
            score[(size_t)(b * 16 + lg * 4 + r) * 16384 + kv0 + w * 64 + ni * 16 + lr] = acc[ni][r];
}

// ---------------- radix top-2048 select per (b,h) ----------------
__global__ __launch_bounds__(256) void select_kernel(const float* __restrict__ score,
                                                     int* __restrict__ sel_idx) {
    int bh = blockIdx.x;
    const float* sc = score + (size_t)bh * 16384;
    __shared__ int hist[256];
    __shared__ int bc[4];
    int tid = threadIdx.x;
    if (tid == 0) { bc[0] = 0; bc[1] = 2048; bc[2] = 0; bc[3] = 0; }
    __syncthreads();
    for (int shift = 24; shift >= 0; shift -= 8) {
        hist[tid] = 0;
        __syncthreads();
        unsigned int prefix = (unsigned int)bc[0];
        unsigned int hi_mask = (shift == 24) ? 0u : (0xFFFFFFFFu << (shift + 8));
        for (int i = tid; i < 16384; i += 256) {
            unsigned int b = __float_as_uint(sc[i]);
            unsigned int ui = (b & 0x80000000u) ? ~b : (b | 0x80000000u);
            if ((ui & hi_mask) == (prefix & hi_mask))
                atomicAdd(&hist[(ui >> shift) & 0xff], 1);
        }
        __syncthreads();
        if (tid == 0) {
            int want = bc[1], acc = 0, d = 0;
            for (int dd = 255; dd >= 0; dd--) {
                acc += hist[dd];
                if (acc >= want) { d = dd; break; }
            }
            bc[1] = want - (acc - hist[d]);
            bc[0] = (int)(prefix | ((unsigned int)d << shift));
        }
        __syncthreads();
    }
    unsigned int uthr = (unsigned int)bc[0];
    int n_eq = bc[1];
    int base_eq = 2048 - n_eq;
    int* out = sel_idx + (size_t)bh * 2048;
    for (int i = tid; i < 16384; i += 256) {
        unsigned int b = __float_as_uint(sc[i]);
        unsigned int ui = (b & 0x80000000u) ? ~b : (b | 0x80000000u);
        if (ui > uthr) {
            int p = atomicAdd(&bc[2], 1);
            out[p] = i;
        } else if (ui == uthr) {
            int p = atomicAdd(&bc[3], 1);
            if (p < n_eq) out[base_eq + p] = i;
        }
    }
}

// ---------------- selected projection: K_sel[t][d] and V_selT[d][t] (chunk-swizzled) ----
__global__ __launch_bounds__(256) void selproj_kernel(const u16* __restrict__ ebf,
                                                      const u16* __restrict__ WkvT,
                                                      const int* __restrict__ sel_idx,
                                                      u16* __restrict__ k_sel,
                                                      u16* __restrict__ v_selT) {
    const int bh = blockIdx.y, b = bh >> 4, h = bh & 15;
    const int t0 = blockIdx.x * 128;
    const int tid = threadIdx.x, w = tid >> 6, l = tid & 63;
    const int lr = l & 15, lg = l >> 4;
    const int lane_row = l >> 3, src_ch = (l & 7) ^ lane_row;

    __shared__ u16 e_lds[128 * 64];
    __shared__ u16 w_lds[128 * 64];

    int encrow[4], wrow[4];
    #pragma unroll
    for (int j = 0; j < 4; j++) {
        int t = t0 + w * 32 + j * 8 + lane_row;
        encrow[j] = b * 16384 + sel_idx[(size_t)bh * 2048 + t];
        int r = w * 32 + j * 8 + lane_row;
        wrow[j] = (r < 64) ? (h * 64 + r) : (1024 + h * 64 + (r & 63));
    }

    const f32x4 fz = {0.f, 0.f, 0.f, 0.f};
    f32x4 acc_k[2][4], acc_v[8];
    #pragma unroll
    for (int i = 0; i < 2; i++)
        #pragma unroll
        for (int j = 0; j < 4; j++) acc_k[i][j] = fz;
    #pragma unroll
    for (int i = 0; i < 8; i++) acc_v[i] = fz;

    for (int kt = 0; kt < 1024; kt += 64) {
        __syncthreads();
        #pragma unroll
        for (int j = 0; j < 4; j++) {
            glds16(ebf + (size_t)encrow[j] * 1024 + kt + src_ch * 8, e_lds + (w * 32 + j * 8) * 64);
            glds16(WkvT + (size_t)wrow[j] * 1024 + kt + src_ch * 8, w_lds + (w * 32 + j * 8) * 64);
        }
        __syncthreads();
        #pragma unroll
        for (int ks = 0; ks < 2; ks++) {
            bf16x8 ae[2];
            #pragma unroll
            for (int mi = 0; mi < 2; mi++) {
                int row = w * 32 + mi * 16 + lr;
                ae[mi] = *(const bf16x8*)(e_lds + row * 64 + (((ks * 4 + lg) ^ (row & 7))) * 8);
            }
            bf16x8 aw;
            {
                int row = 64 + w * 16 + lr;
                aw = *(const bf16x8*)(w_lds + row * 64 + (((ks * 4 + lg) ^ (row & 7))) * 8);
            }
            #pragma unroll
            for (int ni = 0; ni < 4; ni++) {
                int row = ni * 16 + lr;
                bf16x8 bw = *(const bf16x8*)(w_lds + row * 64 + (((ks * 4 + lg) ^ (row & 7))) * 8);
                acc_k[0][ni] = __builtin_amdgcn_mfma_f32_16x16x32_bf16(ae[0], bw, acc_k[0][ni], 0, 0, 0);
                acc_k[1][ni] = __builtin_amdgcn_mfma_f32_16x16x32_bf16(ae[1], bw, acc_k[1][ni], 0, 0, 0);
            }
            #pragma unroll
            for (int ni = 0; ni < 8; ni++) {
                int row = ni * 16 + lr;
                bf16x8 be = *(const bf16x8*)(e_lds + row * 64 + (((ks * 4 + lg) ^ (row & 7))) * 8);
                acc_v[ni] = __builtin_amdgcn_mfma_f32_16x16x32_bf16(aw, be, acc_v[ni], 0, 0, 0);
            }
        }
    }

    u16* kb = k_sel + (size_t)bh * 2048 * 64;
    #pragma unroll
    for (int mi = 0; mi < 2; mi++)
        #pragma unroll
        for (int ni = 0; ni < 4; ni++)
            #pragma unroll
            for (int r = 0; r < 4; r++) {
                int t = t0 + w * 32 + mi * 16 + lg * 4 + r;
                int d = ni * 16 + lr;
                kb[(size_t)t * 64 + (((d >> 3) ^ (t & 7)) * 8) + (d & 7)] = f2bf(acc_k[mi][ni][r]);
            }
    u16* vb = v_selT + (size_t)bh * 64 * 2048;
    #pragma unroll
    for (int ni = 0; ni < 8; ni++)
        #pragma unroll
        for (int r = 0; r < 4; r++) {
            int d = w * 16 + lg * 4 + r;
            int t = t0 + ni * 16 + lr;
            int tl = t & 63;
            vb[(size_t)d * 2048 + (t & ~63) + ((((tl >> 3) ^ (d & 7))) * 8) + (tl & 7)] =
                f2bf(acc_v[ni][r]);
        }
}

// ---------------- flash attention over compacted selected KV ----------------
__global__ __launch_bounds__(256) void attn_kernel(
    const u16* __restrict__ q_bf, const u16* __restrict__ k_sel,
    const u16* __restrict__ v_selT, u16* __restrict__ attn_out) {
    const int bh = blockIdx.y, b = bh >> 4, h = bh & 15;
    const int q0 = blockIdx.x * 64;
    const int tid = threadIdx.x, w = tid >> 6, l = tid & 63;
    const int lr = l & 15, lg = l >> 4;
    const int lk = lr & 7;
    const float SC = 0.18033688011f;   // 0.125 * log2(e)
    const float THR = 11.0f;

    __shared__ u16 k_lds[64 * 64];
    __shared__ u16 vt_lds[64 * 64];
    __shared__ __bf16 p_lds[4][16][72];

    const u16* qb = q_bf + ((size_t)b * 2048 + q0 + w * 16 + lr) * 1024 + h * 64;
    bf16x8 qf0 = *(const bf16x8*)(qb + lg * 8);
    bf16x8 qf1 = *(const bf16x8*)(qb + 32 + lg * 8);

    const f32x4 fz = {0.f, 0.f, 0.f, 0.f};
    f32x4 o[4];
    #pragma unroll
    for (int f = 0; f < 4; f++) o[f] = fz;
    float mm[4] = {-1e30f, -1e30f, -1e30f, -1e30f};
    float l_run[4] = {0.f, 0.f, 0.f, 0.f};

    const u16* kb  = k_sel + (size_t)bh * 2048 * 64;
    const u16* vtb = v_selT + (size_t)bh * 64 * 2048;

    #pragma unroll 1
    for (int it = 0; it < 32; ++it) {
        const int t0 = it * 64;
        const u16* ksrc = kb + (size_t)(t0 + w * 16) * 64 + (size_t)l * 8;
        glds16(ksrc,       k_lds + (w * 16) * 64);
        glds16(ksrc + 512, k_lds + (w * 16 + 8) * 64);
        const u16* vsrc = vtb + (size_t)(w * 16 + (l >> 3)) * 2048 + t0 + (l & 7) * 8;
        glds16(vsrc,            vt_lds + (w * 16) * 64);
        glds16(vsrc + 8 * 2048, vt_lds + (w * 16 + 8) * 64);
        __syncthreads();

        f32x4 s[4];
        #pragma unroll
        for (int c = 0; c < 4; c++) s[c] = fz;
        #pragma unroll
        for (int c = 0; c < 4; c++) {
            const u16* krow = k_lds + (c * 16 + lr) * 64;
            bf16x8 kf0 = *(const bf16x8*)(krow + (lg ^ lk) * 8);
            s[c] = __builtin_amdgcn_mfma_f32_16x16x32_bf16(qf0, kf0, s[c], 0, 0, 0);
            bf16x8 kf1 = *(const bf16x8*)(krow + (((4 + lg) ^ lk)) * 8);
            s[c] = __builtin_amdgcn_mfma_f32_16x16x32_bf16(qf1, kf1, s[c], 0, 0, 0);
        }

        float mx[4];
        #pragma unroll
        for (int r = 0; r < 4; r++) {
            float m0 = fmaxf(fmaxf(s[0][r], s[1][r]), fmaxf(s[2][r], s[3][r]));
            m0 = fmaxf(m0, __shfl_xor(m0, 1));
            m0 = fmaxf(m0, __shfl_xor(m0, 2));
            m0 = fmaxf(m0, __shfl_xor(m0, 4));
            m0 = fmaxf(m0, __shfl_xor(m0, 8));
            mx[r] = m0 * SC;
        }
        bool need = false;
        #pragma unroll
        for (int r = 0; r < 4; r++) need = need || (mx[r] > mm[r] + THR);
        if (__any(need)) {
            #pragma unroll
            for (int r = 0; r < 4; r++) {
                float mn = fmaxf(mm[r], mx[r]);
                float al = __builtin_amdgcn_exp2f(mm[r] - mn);
                mm[r] = mn;
                l_run[r] *= al;
                #pragma unroll
                for (int f = 0; f < 4; f++) o[f][r] *= al;
            }
        }
        float rs[4] = {0.f, 0.f, 0.f, 0.f};
        #pragma unroll
        for (int c = 0; c < 4; c++) {
            #pragma unroll
            for (int r = 0; r < 4; r++) {
                float p = __builtin_amdgcn_exp2f(__builtin_fmaf(s[c][r], SC, -mm[r]));
                rs[r] += p;
                p_lds[w][lg * 4 + r][c * 16 + lr] = (__bf16)p;
            }
        }
        #pragma unroll
        for (int r = 0; r < 4; r++) {
            rs[r] += __shfl_xor(rs[r], 1);
            rs[r] += __shfl_xor(rs[r], 2);
            rs[r] += __shfl_xor(rs[r], 4);
            rs[r] += __shfl_xor(rs[r], 8);
            l_run[r] += rs[r];
        }

        #pragma unroll
        for (int kk = 0; kk < 2; kk++) {
            bf16x8 ap = *(const bf16x8*)(&p_lds[w][lr][kk * 32 + lg * 8]);
            #pragma unroll
            for (int f = 0; f < 4; f++) {
                const u16* vrow = vt_lds + (f * 16 + lr) * 64;
                bf16x8 bv = *(const bf16x8*)(vrow + (((kk * 4 + lg) ^ lk)) * 8);
                o[f] = __builtin_amdgcn_mfma_f32_16x16x32_bf16(ap, bv, o[f], 0, 0, 0);
            }
        }
        __syncthreads();
    }

    float invl[4];
    #pragma unroll
    for (int r = 0; r < 4; r++) invl[r] = 1.f / l_run[r];
    u16* ob = attn_out + ((size_t)b * 2048 + q0 + w * 16 + lg * 4) * 1024 + h * 64 + lr;
    #pragma unroll
    for (int f = 0; f < 4; f++) {
        #pragma unroll
        for (int r = 0; r < 4; r++) {
            __bf16 hv = (__bf16)(o[f][r] * invl[r]);
            ob[(size_t)r * 1024 + f * 16] = *(u16*)&hv;
        }
    }
}

// ---------------- launcher ----------------
extern "C" void kernel_launch(void* const* d_in, const int* in_sizes, int n_in,
                              void* d_out, int out_size, void* d_ws, size_t ws_size,
                              hipStream_t stream) {
    const float* hidden = (const float*)d_in[0];
    const float* enc    = (const float*)d_in[1];
    const float* Wq = (const float*)d_in[2];
    const float* Wk = (const float*)d_in[3];
    const float* Wv = (const float*)d_in[4];
    const float* Wo = (const float*)d_in[5];
    const float* bo = (const float*)d_in[6];
    const float* Wg = (const float*)d_in[7];
    const float* bg = (const float*)d_in[8];
    float* out = (float*)d_out;

    char* ws = (char*)d_ws;
    size_t off = 0;
    auto alloc = [&](size_t bytes) -> char* {
        char* p = ws + off;
        off += (bytes + 255) & ~(size_t)255;
        return p;
    };
    u16* hbf   = (u16*)alloc(4096ull * 1024 * 2);
    u16* ebf   = (u16*)alloc(32768ull * 1024 * 2);
    u16* WqT   = (u16*)alloc(1024ull * 1024 * 2);
    u16* WkvT  = (u16*)alloc(2048ull * 1024 * 2);
    u16* WgT   = (u16*)alloc(1024ull * 1024 * 2);
    u16* WoT   = (u16*)alloc(1024ull * 1024 * 2);
    u16* q_bf  = (u16*)alloc(4096ull * 1024 * 2);
    float* hm  = (float*)alloc(2ull * 1024 * 4);
    float* part = (float*)alloc(2ull * 128 * 1024 * 4);
    u16* z_bf  = (u16*)alloc(32ull * 1024 * 2);
    float* scor = (float*)alloc(32ull * 16384 * 4);
    int* sel    = (int*)alloc(32ull * 2048 * 4);
    u16* ksel   = (u16*)alloc(32ull * 2048 * 64 * 2);
    u16* vT     = (u16*)alloc(32ull * 64 * 2048 * 2);
    u16* attn   = (u16*)alloc(4096ull * 1024 * 2);
    u16* gate   = (u16*)alloc(4096ull * 1024 * 2);
    (void)ws_size; (void)in_sizes; (void)n_in; (void)out_size;

    hsum1_kernel<<<dim3(2, 128), 256, 0, stream>>>(hidden, part);
    hsum2_kernel<<<2, 256, 0, stream>>>(part, hm);
    cast_bf16_kernel<<<4096, 256, 0, stream>>>(hidden, hbf, 1048576);
    cast_bf16_kernel<<<32768, 256, 0, stream>>>(enc, ebf, 8388608);
    transpose_cast_kernel<<<dim3(32, 32, 5), dim3(32, 8), 0, stream>>>(
        Wq, Wk, Wv, Wg, Wo, WqT, WkvT, WgT, WoT);

    qz_kernel<<<32, 256, 0, stream>>>(hm, WqT, WkvT, z_bf);
    score_mfma_kernel<<<dim3(64, 2), 256, 0, stream>>>(ebf, z_bf, scor);
    select_kernel<<<32, 256, 0, stream>>>(scor, sel);
    selproj_kernel<<<dim3(16, 32), 256, 0, stream>>>(ebf, WkvT, sel, ksel, vT);

    gemm_bf16<0><<<dim3(8, 32), 256, 0, stream>>>(hbf, WqT, 1024, q_bf, nullptr, nullptr, nullptr, nullptr);
    attn_kernel<<<dim3(32, 32), 256, 0, stream>>>(q_bf, ksel, vT, attn);

    gemm_bf16<2><<<dim3(8, 32), 256, 0, stream>>>(attn, WgT, 1024, gate, bg, attn, nullptr, nullptr);
    gemm_bf16<3><<<dim3(8, 32), 256, 0, stream>>>(gate, WoT, 1024, nullptr, bo, nullptr, hidden, out);
}